// Round 1
// baseline (73.443 us; speedup 1.0000x reference)
//
#include <hip/hip_runtime.h>

// PiecewiseChebyshevSeries: out[b,n] = sum_m cheb[b, x_idx(b,n), m] * T_m(t(b,n))
// where (x_idx, t) decode z via divmod on domain [-1,1], and
// cos(m*arccos(t)) == T_m(t) -> Chebyshev recurrence, no transcendentals.

constexpr int B = 16;
constexpr int X = 256;
constexpr int Y = 32;
constexpr int N = 131072;

constexpr int THREADS = 256;
constexpr int EPT = 8;                    // elements per thread
constexpr int EPB = THREADS * EPT;        // 2048 elements per block
constexpr int BLOCKS_PER_B = N / EPB;     // 64
constexpr int LSTR = 36;                  // LDS row stride in floats (16B-aligned, 8 bank-groups)

__global__ __launch_bounds__(THREADS, 4)
void cheb_eval(const float* __restrict__ z,
               const float* __restrict__ cheb,
               float* __restrict__ out)
{
    __shared__ float lds[X * LSTR];       // 36 KiB
    const int bid   = blockIdx.x;
    const int b     = bid >> 6;           // / BLOCKS_PER_B
    const int chunk = bid & 63;
    const int tid   = threadIdx.x;

    // Stage cheb[b] (256 x 32 f32 = 32 KiB) into LDS, padded row stride 36.
    const float4* src = reinterpret_cast<const float4*>(cheb + (size_t)b * (X * Y));
    #pragma unroll
    for (int k = 0; k < (X * Y / 4) / THREADS; ++k) {   // 8 iterations
        int f4  = k * THREADS + tid;                    // 0..2047
        float4 v = src[f4];
        int row = f4 >> 3;                              // f4*4/32
        int q   = f4 & 7;
        *reinterpret_cast<float4*>(&lds[row * LSTR + q * 4]) = v;
    }
    __syncthreads();

    const float*  zb  = z   + (size_t)b * N + (size_t)chunk * EPB;
    float*        ob  = out + (size_t)b * N + (size_t)chunk * EPB;
    const float4* zb4 = reinterpret_cast<const float4*>(zb);
    float4*       ob4 = reinterpret_cast<float4*>(ob);

    #pragma unroll
    for (int k = 0; k < EPT / 4; ++k) {                 // 2 iterations
        float4 zv = zb4[k * THREADS + tid];
        float zz[4] = {zv.x, zv.y, zv.z, zv.w};
        float r[4];
        #pragma unroll
        for (int j = 0; j < 4; ++j) {
            // Decode: u = z - a; x = floor(u/2); t = (u - 2x) - 1  (bit-identical to ref)
            float u  = zz[j] + 1.0f;
            float xf = floorf(u * 0.5f);
            int   xi = (int)xf;
            float t  = (u - 2.0f * xf) - 1.0f;

            // Gather the 32-coefficient row from LDS (8 x ds_read_b128).
            const float* c = &lds[xi * LSTR];
            float cr[32];
            #pragma unroll
            for (int q = 0; q < 8; ++q) {
                float4 cv = *reinterpret_cast<const float4*>(&c[q * 4]);
                cr[q * 4 + 0] = cv.x;
                cr[q * 4 + 1] = cv.y;
                cr[q * 4 + 2] = cv.z;
                cr[q * 4 + 3] = cv.w;
            }

            // Chebyshev recurrence: T0=1, T1=t, T_{m+1} = 2t*T_m - T_{m-1}
            float t2  = t + t;
            float Tpp = 1.0f, Tp = t;
            float acc = fmaf(cr[1], t, cr[0]);
            #pragma unroll
            for (int m = 2; m < Y; ++m) {
                float Tn = fmaf(t2, Tp, -Tpp);
                acc = fmaf(cr[m], Tn, acc);
                Tpp = Tp; Tp = Tn;
            }
            r[j] = acc;
        }
        ob4[k * THREADS + tid] = make_float4(r[0], r[1], r[2], r[3]);
    }
}

extern "C" void kernel_launch(void* const* d_in, const int* in_sizes, int n_in,
                              void* d_out, int out_size, void* d_ws, size_t ws_size,
                              hipStream_t stream) {
    const float* z    = (const float*)d_in[0];
    const float* cheb = (const float*)d_in[1];
    float*       out  = (float*)d_out;
    dim3 grid(B * BLOCKS_PER_B);   // 1024 blocks
    dim3 block(THREADS);
    hipLaunchKernelGGL(cheb_eval, grid, block, 0, stream, z, cheb, out);
}

// Round 2
// 72.784 us; speedup vs baseline: 1.0091x; 1.0091x over previous
//
#include <hip/hip_runtime.h>

// PiecewiseChebyshevSeries: out[b,n] = sum_m cheb[b, x_idx(b,n), m] * T_m(t(b,n))
// cos(m*arccos(t)) == T_m(t) -> Chebyshev three-term recurrence, no transcendentals.
// R2: stream coefficients float4-at-a-time through the recurrence (no cr[32]
// array) to kill VGPR spill under the __launch_bounds__(256,4) 128-reg cap.

constexpr int B = 16;
constexpr int X = 256;
constexpr int Y = 32;
constexpr int N = 131072;

constexpr int THREADS = 256;
constexpr int EPT = 8;                    // elements per thread
constexpr int EPB = THREADS * EPT;        // 2048 elements per block
constexpr int BLOCKS_PER_B = N / EPB;     // 64
constexpr int LSTR = 36;                  // LDS row stride in floats (16B-aligned, spreads banks)

__global__ __launch_bounds__(THREADS, 4)
void cheb_eval(const float* __restrict__ z,
               const float* __restrict__ cheb,
               float* __restrict__ out)
{
    __shared__ float lds[X * LSTR];       // 36 KiB -> 4 blocks/CU, 16 waves/CU
    const int bid   = blockIdx.x;
    const int b     = bid >> 6;           // / BLOCKS_PER_B
    const int chunk = bid & 63;
    const int tid   = threadIdx.x;

    // Stage cheb[b] (256 x 32 f32 = 32 KiB) into LDS, padded row stride 36.
    const float4* src = reinterpret_cast<const float4*>(cheb + (size_t)b * (X * Y));
    #pragma unroll
    for (int k = 0; k < (X * Y / 4) / THREADS; ++k) {   // 8 iterations
        int f4  = k * THREADS + tid;                    // 0..2047
        float4 v = src[f4];
        int row = f4 >> 3;
        int q   = f4 & 7;
        *reinterpret_cast<float4*>(&lds[row * LSTR + q * 4]) = v;
    }
    __syncthreads();

    const float4* zb4 = reinterpret_cast<const float4*>(z   + (size_t)b * N + (size_t)chunk * EPB);
    float4*       ob4 = reinterpret_cast<float4*>      (out + (size_t)b * N + (size_t)chunk * EPB);

    #pragma unroll
    for (int k = 0; k < EPT / 4; ++k) {                 // 2 iterations
        float4 zv = zb4[k * THREADS + tid];
        float zz[4] = {zv.x, zv.y, zv.z, zv.w};
        float r[4];
        #pragma unroll
        for (int j = 0; j < 4; ++j) {
            // Decode: u = z + 1; x = floor(u/2); t = (u - 2x) - 1  (matches ref divmod)
            float u  = zz[j] + 1.0f;
            float xf = floorf(u * 0.5f);
            int   xi = (int)xf;
            float t  = fmaf(-2.0f, xf, u) - 1.0f;

            const float4* c4 = reinterpret_cast<const float4*>(&lds[xi * LSTR]);
            float t2 = t + t;

            // First quad: T0=1, T1=t, T2, T3
            float4 v0 = c4[0];
            float acc = fmaf(v0.y, t, v0.x);
            float Tpp = t;                      // T1
            float Tp  = fmaf(t2, t, -1.0f);     // T2
            acc = fmaf(v0.z, Tp, acc);
            float Tn  = fmaf(t2, Tp, -Tpp);     // T3
            acc = fmaf(v0.w, Tn, acc);
            Tpp = Tp; Tp = Tn;

            // Remaining 7 quads, streamed: only one float4 of coeffs live at a time.
            #pragma unroll
            for (int q = 1; q < 8; ++q) {
                float4 v = c4[q];
                Tn = fmaf(t2, Tp, -Tpp); acc = fmaf(v.x, Tn, acc); Tpp = Tp; Tp = Tn;
                Tn = fmaf(t2, Tp, -Tpp); acc = fmaf(v.y, Tn, acc); Tpp = Tp; Tp = Tn;
                Tn = fmaf(t2, Tp, -Tpp); acc = fmaf(v.z, Tn, acc); Tpp = Tp; Tp = Tn;
                Tn = fmaf(t2, Tp, -Tpp); acc = fmaf(v.w, Tn, acc); Tpp = Tp; Tp = Tn;
            }
            r[j] = acc;
        }
        ob4[k * THREADS + tid] = make_float4(r[0], r[1], r[2], r[3]);
    }
}

extern "C" void kernel_launch(void* const* d_in, const int* in_sizes, int n_in,
                              void* d_out, int out_size, void* d_ws, size_t ws_size,
                              hipStream_t stream) {
    const float* z    = (const float*)d_in[0];
    const float* cheb = (const float*)d_in[1];
    float*       out  = (float*)d_out;
    dim3 grid(B * BLOCKS_PER_B);   // 1024 blocks
    dim3 block(THREADS);
    hipLaunchKernelGGL(cheb_eval, grid, block, 0, stream, z, cheb, out);
}

// Round 3
// 67.009 us; speedup vs baseline: 1.0960x; 1.0862x over previous
//
#include <hip/hip_runtime.h>

// PiecewiseChebyshevSeries: out[b,n] = sum_m cheb[b, x_idx(b,n), m] * T_m(t(b,n))
// cos(m*arccos(t)) == T_m(t) -> Chebyshev three-term recurrence, no transcendentals.
// R3: f16 coefficients in LDS (20480 B -> 8 blocks/CU = 32 waves/CU, 100% occupancy;
// halves LDS gather bytes: 4x ds_read_b128 per element). Grid 2048, EPT=4.
// Decode path stays bit-exact vs the JAX divmod reference; f16 coeff quantization
// adds ~3e-3 abs error vs 0.0625 threshold.

constexpr int B = 16;
constexpr int X = 256;
constexpr int Y = 32;
constexpr int N = 131072;

constexpr int THREADS = 256;
constexpr int EPT = 4;                    // elements per thread
constexpr int EPB = THREADS * EPT;        // 1024 elements per block
constexpr int BLOCKS_PER_B = N / EPB;     // 128
constexpr int LSTR = 40;                  // f16 row stride (80 B: 16B-aligned, spreads 8 bank-groups)

typedef _Float16 half4v __attribute__((ext_vector_type(4)));
typedef _Float16 half8v __attribute__((ext_vector_type(8)));

__device__ __forceinline__ float eval1(const _Float16* __restrict__ lds, float zj)
{
    // Decode: u = z + 1; x = floor(u/2); t = (u - 2x) - 1   (bit-exact vs ref divmod)
    float u  = zj + 1.0f;
    float xf = floorf(u * 0.5f);
    int   xi = (int)xf;
    float t  = fmaf(-2.0f, xf, u) - 1.0f;

    const half8v* c8 = reinterpret_cast<const half8v*>(lds + xi * LSTR);
    half8v h[4];
    #pragma unroll
    for (int i = 0; i < 4; ++i) h[i] = c8[i];     // 4x ds_read_b128

    float t2  = t + t;
    float Tpp = t;                                 // T1
    float acc = fmaf((float)h[0][1], t, (float)h[0][0]);
    float Tp  = fmaf(t2, t, -1.0f);                // T2
    acc = fmaf((float)h[0][2], Tp, acc);
    #pragma unroll
    for (int m = 3; m < 32; ++m) {                 // static h indices after unroll
        float Tn = fmaf(t2, Tp, -Tpp);
        acc = fmaf((float)h[m >> 3][m & 7], Tn, acc);
        Tpp = Tp; Tp = Tn;
    }
    return acc;
}

__global__ __launch_bounds__(THREADS, 8)
void cheb_eval(const float* __restrict__ z,
               const float* __restrict__ cheb,
               float* __restrict__ out)
{
    __shared__ __align__(16) _Float16 lds[X * LSTR];   // 20480 B
    const int bid   = blockIdx.x;
    const int b     = bid >> 7;            // / BLOCKS_PER_B
    const int chunk = bid & 127;
    const int tid   = threadIdx.x;

    // Stage cheb[b] (256 x 32 f32) into LDS as f16, row stride 40.
    const float4* src = reinterpret_cast<const float4*>(cheb + (size_t)b * (X * Y));
    #pragma unroll
    for (int k = 0; k < (X * Y / 4) / THREADS; ++k) {   // 8 iterations
        int f4  = k * THREADS + tid;
        float4 v = src[f4];
        int row = f4 >> 3;
        int q   = f4 & 7;
        half4v hv = { (_Float16)v.x, (_Float16)v.y, (_Float16)v.z, (_Float16)v.w };
        *reinterpret_cast<half4v*>(&lds[row * LSTR + q * 4]) = hv;   // 8B ds_write
    }
    __syncthreads();

    const float4* zb4 = reinterpret_cast<const float4*>(z   + (size_t)b * N + (size_t)chunk * EPB);
    float4*       ob4 = reinterpret_cast<float4*>      (out + (size_t)b * N + (size_t)chunk * EPB);

    float4 zv = zb4[tid];
    float r0, r1, r2, r3;
    // Two register-lean pairs (keeps VGPR under the 64-cap for 8 waves/SIMD).
    r0 = eval1(lds, zv.x);
    r1 = eval1(lds, zv.y);
    r2 = eval1(lds, zv.z);
    r3 = eval1(lds, zv.w);
    ob4[tid] = make_float4(r0, r1, r2, r3);
}

extern "C" void kernel_launch(void* const* d_in, const int* in_sizes, int n_in,
                              void* d_out, int out_size, void* d_ws, size_t ws_size,
                              hipStream_t stream) {
    const float* z    = (const float*)d_in[0];
    const float* cheb = (const float*)d_in[1];
    float*       out  = (float*)d_out;
    dim3 grid(B * BLOCKS_PER_B);   // 2048 blocks -> 8 blocks/CU
    dim3 block(THREADS);
    hipLaunchKernelGGL(cheb_eval, grid, block, 0, stream, z, cheb, out);
}